// Round 3
// baseline (422.326 us; speedup 1.0000x reference)
//
#include <hip/hip_runtime.h>

#define KK 16
#define DD 15          // K-1
#define NPIX (2048*2048)

typedef float v4f __attribute__((ext_vector_type(4)));

__global__ __launch_bounds__(256) void gum_kernel(
    const float* __restrict__ z,      // (DD, NPIX)
    const float* __restrict__ vert,   // (KK, DD) row-major
    float* __restrict__ out)          // [0,NPIX) = X as float, [NPIX,2*NPIX) = dmin
{
    // vS[k][0..14] = vertex k, vS[k][15] = ||v_k||^2. 64B rows -> ds_read_b128.
    __shared__ float vS[KK][16];

    const int t = threadIdx.x;
    if (t < KK) {
        float s = 0.0f;
        #pragma unroll
        for (int d = 0; d < DD; ++d) {
            float v = vert[t * DD + d];
            vS[t][d] = v;
            s += v * v;
        }
        vS[t][DD] = s;
    }
    __syncthreads();

    const int gid  = blockIdx.x * blockDim.x + t;  // pixel-group id (4 pixels)
    const size_t base = (size_t)gid * 4;

    // Non-temporal streaming loads: nt lines are evict-first in L2/L3, so we
    // recycle our own ways instead of force-evicting the harness's dirty
    // 960 MiB poison resident in the Infinity Cache (one dirty writeback per
    // set instead of per line). All 15 loads independent, in flight together.
    v4f zv[DD];
    #pragma unroll
    for (int d = 0; d < DD; ++d)
        zv[d] = __builtin_nontemporal_load((const v4f*)(z + (size_t)d * NPIX + base));

    float zz[4] = {0.f, 0.f, 0.f, 0.f};
    #pragma unroll
    for (int d = 0; d < DD; ++d) {
        #pragma unroll
        for (int c = 0; c < 4; ++c) zz[c] += zv[d][c] * zv[d][c];
    }

    // Argmin on d^2 (sqrt deferred): sqrt is correctly rounded and monotone,
    // so argmin/min commute exactly. Only one d2 can be negative (vertices
    // are pairwise far apart), so the max(,0) clamp can't create a tie that
    // changes the first-occurrence winner.
    float bestd2[4] = {3.0e38f, 3.0e38f, 3.0e38f, 3.0e38f};
    int   bestk[4]  = {0, 0, 0, 0};

    #pragma unroll
    for (int k = 0; k < KK; ++k) {
        float vk[16];
        *(v4f*)&vk[0]  = *(const v4f*)&vS[k][0];   // ds_read_b128 x4
        *(v4f*)&vk[4]  = *(const v4f*)&vS[k][4];
        *(v4f*)&vk[8]  = *(const v4f*)&vS[k][8];
        *(v4f*)&vk[12] = *(const v4f*)&vS[k][12];  // vk[15] = vv_k

        float cr[4] = {0.f, 0.f, 0.f, 0.f};
        #pragma unroll
        for (int d = 0; d < DD; ++d) {
            #pragma unroll
            for (int c = 0; c < 4; ++c) cr[c] += vk[d] * zv[d][c];
        }

        const float vvk = vk[15];
        #pragma unroll
        for (int c = 0; c < 4; ++c) {
            // match ref evaluation order: (zz - 2*cross) + vv
            float d2 = (zz[c] - 2.0f * cr[c]) + vvk;
            if (d2 < bestd2[c]) { bestd2[c] = d2; bestk[c] = k; }  // first-min tie-break
        }
    }

    v4f xo, dm;
    #pragma unroll
    for (int c = 0; c < 4; ++c) {
        xo[c] = (float)bestk[c];
        dm[c] = sqrtf(fmaxf(bestd2[c], 0.0f));
    }

    __builtin_nontemporal_store(xo, (v4f*)(out + base));
    __builtin_nontemporal_store(dm, (v4f*)(out + NPIX + base));
}

extern "C" void kernel_launch(void* const* d_in, const int* in_sizes, int n_in,
                              void* d_out, int out_size, void* d_ws, size_t ws_size,
                              hipStream_t stream) {
    const float* z    = (const float*)d_in[0];   // (15, 2048, 2048) fp32
    const float* vert = (const float*)d_in[1];   // (16, 15) fp32
    float* out = (float*)d_out;                  // 2 * NPIX floats

    const int npix    = in_sizes[0] / DD;        // 4194304
    const int threads = 256;
    const int groups  = npix / 4;                // 4 pixels per thread
    const int blocks  = (groups + threads - 1) / threads;  // 4096

    gum_kernel<<<blocks, threads, 0, stream>>>(z, vert, out);
}

// Round 4
// 369.309 us; speedup vs baseline: 1.1436x; 1.1436x over previous
//
#include <hip/hip_runtime.h>

#define KK 16
#define DD 15          // K-1
#define NPIX (2048*2048)

typedef float v4f __attribute__((ext_vector_type(4)));

__global__ __launch_bounds__(256, 4) void gum_kernel(
    const float* __restrict__ z,      // (DD, NPIX)
    const float* __restrict__ vert,   // (KK, DD) row-major
    float* __restrict__ out)          // [0,NPIX) = X as float, [NPIX,2*NPIX) = dmin
{
    // Only ||v_k||^2 lives in LDS (no scalar FP unit). Vertices themselves are
    // read via uniform-index loads -> s_load -> SGPR operands in the FMAs.
    __shared__ float vvS[KK];

    const int t = threadIdx.x;
    if (t < KK) {
        float s = 0.0f;
        #pragma unroll
        for (int d = 0; d < DD; ++d) {
            float v = vert[t * DD + d];
            s += v * v;
        }
        vvS[t] = s;
    }
    __syncthreads();

    const int gid  = blockIdx.x * blockDim.x + t;  // pixel-group id (4 pixels)
    const size_t base = (size_t)gid * 4;

    // All 15 plane loads independent and in flight together. Plain (cached)
    // loads: the harness's own z-restore leaves z L3-resident — keep hitting it.
    v4f zv[DD];
    #pragma unroll
    for (int d = 0; d < DD; ++d)
        zv[d] = *(const v4f*)(z + (size_t)d * NPIX + base);

    float zz[4] = {0.f, 0.f, 0.f, 0.f};
    #pragma unroll
    for (int d = 0; d < DD; ++d) {
        #pragma unroll
        for (int c = 0; c < 4; ++c) zz[c] += zv[d][c] * zv[d][c];
    }

    float bestd2[4] = {3.0e38f, 3.0e38f, 3.0e38f, 3.0e38f};
    int   bestk[4]  = {0, 0, 0, 0};

    #pragma unroll
    for (int k = 0; k < KK; ++k) {
        float cr[4] = {0.f, 0.f, 0.f, 0.f};
        #pragma unroll
        for (int d = 0; d < DD; ++d) {
            // vert index is compile-time uniform after unroll -> scalar load,
            // FMA reads the SGPR directly (1 SGPR operand allowed per VALU op).
            const float vkd = vert[k * DD + d];
            #pragma unroll
            for (int c = 0; c < 4; ++c) cr[c] += vkd * zv[d][c];
        }

        const float vvk = vvS[k];   // broadcast ds_read_b32, conflict-free
        #pragma unroll
        for (int c = 0; c < 4; ++c) {
            // same evaluation order as ref: (zz - 2*cross) + vv
            float d2 = (zz[c] - 2.0f * cr[c]) + vvk;
            if (d2 < bestd2[c]) { bestd2[c] = d2; bestk[c] = k; }  // first-min tie-break
        }
    }

    v4f xo, dm;
    #pragma unroll
    for (int c = 0; c < 4; ++c) {
        xo[c] = (float)bestk[c];
        dm[c] = sqrtf(fmaxf(bestd2[c], 0.0f));
    }

    // nt stores: out is write-once — don't let it evict L3-resident z.
    __builtin_nontemporal_store(xo, (v4f*)(out + base));
    __builtin_nontemporal_store(dm, (v4f*)(out + NPIX + base));
}

extern "C" void kernel_launch(void* const* d_in, const int* in_sizes, int n_in,
                              void* d_out, int out_size, void* d_ws, size_t ws_size,
                              hipStream_t stream) {
    const float* z    = (const float*)d_in[0];   // (15, 2048, 2048) fp32
    const float* vert = (const float*)d_in[1];   // (16, 15) fp32
    float* out = (float*)d_out;                  // 2 * NPIX floats

    const int npix    = in_sizes[0] / DD;        // 4194304
    const int threads = 256;
    const int groups  = npix / 4;                // 4 pixels per thread
    const int blocks  = (groups + threads - 1) / threads;  // 4096

    gum_kernel<<<blocks, threads, 0, stream>>>(z, vert, out);
}

// Round 5
// 360.823 us; speedup vs baseline: 1.1705x; 1.0235x over previous
//
#include <hip/hip_runtime.h>

#define KK 16
#define DD 15          // K-1
#define NPIX (2048*2048)

typedef float v2f __attribute__((ext_vector_type(2)));

__global__ __launch_bounds__(256, 8) void gum_kernel(
    const float* __restrict__ z,      // (DD, NPIX)
    const float* __restrict__ vert,   // (KK, DD) row-major
    float* __restrict__ out)          // [0,NPIX) = X as float, [NPIX,2*NPIX) = dmin
{
    // Only ||v_k||^2 in LDS (broadcast ds_read_b32). Vertex components are
    // uniform-indexed -> s_load -> SGPR operand folded into v_pk_fma.
    __shared__ float vvS[KK];

    const int t = threadIdx.x;
    if (t < KK) {
        float s = 0.0f;
        #pragma unroll
        for (int d = 0; d < DD; ++d) {
            float v = vert[t * DD + d];
            s += v * v;
        }
        vvS[t] = s;
    }
    __syncthreads();

    const int gid  = blockIdx.x * blockDim.x + t;  // pixel-pair id
    const size_t base = (size_t)gid * 2;

    // 15 independent dwordx2 loads, all in flight (saddr form: per-plane base
    // in SGPRs, shared voffset). 2 px/thread keeps zv at 30 VGPRs -> 8 waves/SIMD.
    v2f zv[DD];
    #pragma unroll
    for (int d = 0; d < DD; ++d)
        zv[d] = *(const v2f*)(z + (size_t)d * NPIX + base);

    v2f zz = {0.f, 0.f};
    #pragma unroll
    for (int d = 0; d < DD; ++d)
        zz += zv[d] * zv[d];                       // v_pk_fma_f32

    v2f bestd2 = {3.0e38f, 3.0e38f};
    int bestk0 = 0, bestk1 = 0;

    #pragma unroll
    for (int k = 0; k < KK; ++k) {
        v2f cr = {0.f, 0.f};
        #pragma unroll
        for (int d = 0; d < DD; ++d) {
            const float vkd = vert[k * DD + d];    // scalar (SGPR) broadcast
            cr += vkd * zv[d];                     // v_pk_fma_f32, SGPR src splat
        }
        const float vvk = vvS[k];
        // same evaluation order as ref: (zz - 2*cross) + vv; argmin on d^2
        // (sqrt monotone & correctly rounded -> identical argmin/min).
        v2f d2 = (zz - 2.0f * cr) + vvk;
        if (d2.x < bestd2.x) { bestd2.x = d2.x; bestk0 = k; }  // first-min tie-break
        if (d2.y < bestd2.y) { bestd2.y = d2.y; bestk1 = k; }
    }

    v2f xo, dm;
    xo.x = (float)bestk0;
    xo.y = (float)bestk1;
    dm.x = sqrtf(fmaxf(bestd2.x, 0.0f));
    dm.y = sqrtf(fmaxf(bestd2.y, 0.0f));

    // nt stores: out is write-once — don't evict L3-resident z.
    __builtin_nontemporal_store(xo, (v2f*)(out + base));
    __builtin_nontemporal_store(dm, (v2f*)(out + NPIX + base));
}

extern "C" void kernel_launch(void* const* d_in, const int* in_sizes, int n_in,
                              void* d_out, int out_size, void* d_ws, size_t ws_size,
                              hipStream_t stream) {
    const float* z    = (const float*)d_in[0];   // (15, 2048, 2048) fp32
    const float* vert = (const float*)d_in[1];   // (16, 15) fp32
    float* out = (float*)d_out;                  // 2 * NPIX floats

    const int npix    = in_sizes[0] / DD;        // 4194304
    const int threads = 256;
    const int pairs   = npix / 2;                // 2 pixels per thread
    const int blocks  = (pairs + threads - 1) / threads;   // 8192

    gum_kernel<<<blocks, threads, 0, stream>>>(z, vert, out);
}